// Round 7
// baseline (423.256 us; speedup 1.0000x reference)
//
#include <hip/hip_runtime.h>

#define NUM_EDGE_TYPES 38
#define NUM_NODE_TYPES 4
#define HIDDEN 64
#define TABLE_SIZE (NUM_EDGE_TYPES * NUM_NODE_TYPES * NUM_NODE_TYPES)  // 608

// ---- fused: zero base[] + compute sigmoid(gelu)->table wave-parallel ----
// Entry e = (et<<4)|(ht<<2)|tt ; one 64-lane wave computes one entry's
// 64-wide dot product. First 152 blocks (x4 waves) cover all 608 entries.
__global__ __launch_bounds__(256)
void table_zero_kernel(const float* __restrict__ W1, const float* __restrict__ b1,
                       const float* __restrict__ W2, const float* __restrict__ b2,
                       float* __restrict__ table, float* __restrict__ base, int N) {
    for (int i = blockIdx.x * blockDim.x + threadIdx.x; i < N;
         i += gridDim.x * blockDim.x)
        base[i] = 0.0f;

    int wid = threadIdx.x >> 6, lane = threadIdx.x & 63;
    int e = blockIdx.x * 4 + wid;
    if (e < TABLE_SIZE) {
        int et = e >> 4, ht = (e >> 2) & 3, tt = e & 3;
        float h = W1[et * HIDDEN + lane]
                + W1[(NUM_EDGE_TYPES + ht) * HIDDEN + lane]
                + W1[(NUM_EDGE_TYPES + NUM_NODE_TYPES + tt) * HIDDEN + lane]
                + b1[lane];
        float u = 0.7978845608028654f * (h + 0.044715f * h * h * h);
        float g = 0.5f * h * (1.0f + tanhf(u));
        float v = g * W2[lane];
        v += __shfl_xor(v, 32, 64);
        v += __shfl_xor(v, 16, 64);
        v += __shfl_xor(v, 8, 64);
        v += __shfl_xor(v, 4, 64);
        v += __shfl_xor(v, 2, 64);
        v += __shfl_xor(v, 1, 64);
        if (lane == 0) table[e] = 1.0f / (1.0f + expf(-(v + b2[0])));
    }
}

// ---- base (= hop 1 input): edge-parallel, 4 edges/thread int4, LDS table,
// global float atomics onto base[] (L2-resident, 100K addresses). ----
__global__ __launch_bounds__(256)
void edge_base_kernel(const int* __restrict__ src, const int* __restrict__ dst,
                      const int* __restrict__ etype, const int* __restrict__ ntype,
                      const float* __restrict__ table, float* __restrict__ base, int E) {
    __shared__ float tbl[TABLE_SIZE];
    for (int i = threadIdx.x; i < TABLE_SIZE; i += 256) tbl[i] = table[i];
    __syncthreads();
    int e0 = (blockIdx.x * 256 + threadIdx.x) * 4;
    if (e0 + 3 < E) {
        int4 s = *(const int4*)(src + e0);
        int4 d = *(const int4*)(dst + e0);
        int4 t = *(const int4*)(etype + e0);
        int hs0 = ntype[s.x], hs1 = ntype[s.y], hs2 = ntype[s.z], hs3 = ntype[s.w];
        int hd0 = ntype[d.x], hd1 = ntype[d.y], hd2 = ntype[d.z], hd3 = ntype[d.w];
        atomicAdd(base + d.x, tbl[(t.x << 4) | (hs0 << 2) | hd0]);
        atomicAdd(base + d.y, tbl[(t.y << 4) | (hs1 << 2) | hd1]);
        atomicAdd(base + d.z, tbl[(t.z << 4) | (hs2 << 2) | hd2]);
        atomicAdd(base + d.w, tbl[(t.w << 4) | (hs3 << 2) | hd3]);
    } else {
        for (int e = e0; e < E; ++e) {
            int s = src[e], d = dst[e];
            atomicAdd(base + d, tbl[(etype[e] << 4) | (ntype[s] << 2) | ntype[d]]);
        }
    }
}

// ---- fanout: pre-initialize every hop's output buffer with base ----
__global__ __launch_bounds__(256)
void fanout_kernel(const float* __restrict__ base, float* __restrict__ a,
                   float* __restrict__ b, float* __restrict__ o, int N) {
    int i = blockIdx.x * 256 + threadIdx.x;
    if (i < N) {
        float v = base[i];
        a[i] = v;
        b[i] = v;
        o[i] = v;
    }
}

// ---- hops 2-4: next[d] += prev[s]; next pre-initialized to base.
// Edge-parallel int4; gathers + atomics both land in L2 (400KB arrays). ----
__global__ __launch_bounds__(256)
void edge_hop_kernel(const int* __restrict__ src, const int* __restrict__ dst,
                     const float* __restrict__ prev, float* __restrict__ next, int E) {
    int e0 = (blockIdx.x * 256 + threadIdx.x) * 4;
    if (e0 + 3 < E) {
        int4 s = *(const int4*)(src + e0);
        int4 d = *(const int4*)(dst + e0);
        float g0 = prev[s.x];
        float g1 = prev[s.y];
        float g2 = prev[s.z];
        float g3 = prev[s.w];
        atomicAdd(next + d.x, g0);
        atomicAdd(next + d.y, g1);
        atomicAdd(next + d.z, g2);
        atomicAdd(next + d.w, g3);
    } else {
        for (int e = e0; e < E; ++e)
            atomicAdd(next + dst[e], prev[src[e]]);
    }
}

extern "C" void kernel_launch(void* const* d_in, const int* in_sizes, int n_in,
                              void* d_out, int out_size, void* d_ws, size_t ws_size,
                              hipStream_t stream) {
    const int* edge_index = (const int*)d_in[0];   // (2, E)
    const int* etype      = (const int*)d_in[1];   // (E,)
    const int* ntype      = (const int*)d_in[2];   // (N,)
    const float* W1       = (const float*)d_in[3];
    const float* b1       = (const float*)d_in[4];
    const float* W2       = (const float*)d_in[5];
    const float* b2       = (const float*)d_in[6];

    const int E = in_sizes[1];
    const int N = in_sizes[2];
    const int* src = edge_index;
    const int* dst = edge_index + E;
    float* out = (float*)d_out;

    // ws layout (4B units): table[1024] | base[N] | bufA[N] | bufB[N]
    float* table = (float*)d_ws;
    float* base  = table + 1024;
    float* bufA  = base + N;
    float* bufB  = bufA + N;

    const int nb = (N + 255) / 256;                     // 391
    const int tz = max(nb, (TABLE_SIZE + 3) / 4);       // covers table + base zero
    const int eb = (E + 1023) / 1024;                   // 4 edges/thread

    table_zero_kernel<<<tz, 256, 0, stream>>>(W1, b1, W2, b2, table, base, N);
    edge_base_kernel<<<eb, 256, 0, stream>>>(src, dst, etype, ntype, table, base, E);
    fanout_kernel<<<nb, 256, 0, stream>>>(base, bufA, bufB, out, N);
    edge_hop_kernel<<<eb, 256, 0, stream>>>(src, dst, base, bufA, E);   // y2 into bufA
    edge_hop_kernel<<<eb, 256, 0, stream>>>(src, dst, bufA, bufB, E);   // y3 into bufB
    edge_hop_kernel<<<eb, 256, 0, stream>>>(src, dst, bufB, out, E);    // y4 into out
}

// Round 9
// 137.781 us; speedup vs baseline: 3.0719x; 3.0719x over previous
//
#include <hip/hip_runtime.h>

#define NUM_EDGE_TYPES 38
#define NUM_NODE_TYPES 4
#define HIDDEN 64
#define TABLE_SIZE (NUM_EDGE_TYPES * NUM_NODE_TYPES * NUM_NODE_TYPES)  // 608
#define SRC_BITS 17
#define SRC_MASK ((1 << SRC_BITS) - 1)   // N_NODES = 100000 < 131072
#define BSHIFT 8                          // 256 dst nodes per bucket (best measured)
#define BNODES 256
#define MAXB 512                          // supports N up to 131072
#define PB 512                            // partition block size
#define EPT 8                             // edges per thread in partition
#define CHUNK (PB * EPT)                  // 4096 edges per chunk (r4 claim config, verified)
#define HB 1024                           // sort block size
#define CAPC 6144                         // max bucket capacity (LDS sort)
// pack layout: [31]=0 | et[30:25] | dstLow[24:17] | src[16:0]

__device__ __forceinline__ float table_entry(int i, const float* __restrict__ W1,
                                             const float* __restrict__ b1,
                                             const float* __restrict__ W2,
                                             const float* __restrict__ b2) {
    int et = i >> 4, ht = (i >> 2) & 3, tt = i & 3;
    const float* r0 = W1 + et * HIDDEN;
    const float* r1 = W1 + (NUM_EDGE_TYPES + ht) * HIDDEN;
    const float* r2 = W1 + (NUM_EDGE_TYPES + NUM_NODE_TYPES + tt) * HIDDEN;
    float acc = b2[0];
#pragma unroll 8
    for (int k = 0; k < HIDDEN; ++k) {
        float h = r0[k] + r1[k] + r2[k] + b1[k];
        float u = 0.7978845608028654f * (h + 0.044715f * h * h * h);
        float g = 0.5f * h * (1.0f + tanhf(u));
        acc += g * W2[k];
    }
    return 1.0f / (1.0f + expf(-acc));
}

// standalone table (fallback path)
__global__ void table_kernel(const float* __restrict__ W1, const float* __restrict__ b1,
                             const float* __restrict__ W2, const float* __restrict__ b2,
                             float* __restrict__ table) {
    int i = blockIdx.x * blockDim.x + threadIdx.x;
    if (i < TABLE_SIZE) table[i] = table_entry(i, W1, b1, W2, b2);
}

// ---- partition v2: LDS-staged multisplit. Per 4096-edge chunk: LDS hist by
// bucket -> wave-0 scan -> ONE global claim per bucket (r4-verified volume) ->
// LDS rank-scatter into stage[] ordered by bucket -> COALESCED drain to pack
// (thread j writes stage[j] to locS[bk]+(j-bkOff[bk]); consecutive threads ->
// consecutive addresses within each bucket run). Replaces 1.6M scattered 4B
// stores with contiguous runs. Blocks 0-7 also compute the table. ----
__global__ __launch_bounds__(PB)
void partition_kernel(const int* __restrict__ src, const int* __restrict__ dst,
                      const int* __restrict__ etype, int* __restrict__ cursor,
                      int* __restrict__ pack, int E, int nbk, int cap,
                      const float* __restrict__ W1, const float* __restrict__ b1,
                      const float* __restrict__ W2, const float* __restrict__ b2,
                      float* __restrict__ table) {
    __shared__ int hist[MAXB];        // counts, then reused as rank cursor
    __shared__ int bkOff[MAXB + 1];   // exclusive scan of counts
    __shared__ int locS[MAXB];        // claimed global start per bucket
    __shared__ int stage[CHUNK];      // bucket-ordered pack words (16 KB)
    int tid = threadIdx.x;
    for (int i = tid; i < MAXB; i += PB) hist[i] = 0;
    __syncthreads();
    int start = blockIdx.x * CHUNK;
    int end = min(start + CHUNK, E);
    if (end - start == CHUNK) {               // full chunk: 8 edges/thread
        int4 dv[2], sv[2], ev[2];
#pragma unroll
        for (int g = 0; g < 2; ++g) {
            int j = start + g * (PB * 4) + tid * 4;
            dv[g] = *(const int4*)(dst + j);
            sv[g] = *(const int4*)(src + j);
            ev[g] = *(const int4*)(etype + j);
        }
#pragma unroll
        for (int g = 0; g < 2; ++g) {
            atomicAdd(&hist[dv[g].x >> BSHIFT], 1);
            atomicAdd(&hist[dv[g].y >> BSHIFT], 1);
            atomicAdd(&hist[dv[g].z >> BSHIFT], 1);
            atomicAdd(&hist[dv[g].w >> BSHIFT], 1);
        }
        __syncthreads();
        // wave 0: exclusive scan of 512 counts (8 per lane)
        if (tid < 64) {
            int bi = tid * 8;
            int v[8]; int s = 0;
#pragma unroll
            for (int k = 0; k < 8; ++k) { v[k] = hist[bi + k]; s += v[k]; }
            int inc = s;
            for (int d = 1; d < 64; d <<= 1) {
                int t = __shfl_up(inc, d, 64);
                if (tid >= d) inc += t;
            }
            int excl = inc - s;
#pragma unroll
            for (int k = 0; k < 8; ++k) { bkOff[bi + k] = excl; excl += v[k]; }
            if (tid == 63) bkOff[MAXB] = inc;
        }
        // one global claim per bucket (reads hist; concurrent with scan - no hazard)
        for (int i = tid; i < nbk; i += PB) {
            int h = hist[i];
            locS[i] = h ? i * cap + atomicAdd(&cursor[i], h) : 0;
        }
        __syncthreads();
        for (int i = tid; i < MAXB; i += PB) hist[i] = 0;   // reuse as rank cursor
        __syncthreads();
        // rank-scatter into stage (LDS->LDS)
#pragma unroll
        for (int g = 0; g < 2; ++g) {
            int w0 = (ev[g].x << (SRC_BITS + 8)) | ((dv[g].x & (BNODES - 1)) << SRC_BITS) | sv[g].x;
            int w1 = (ev[g].y << (SRC_BITS + 8)) | ((dv[g].y & (BNODES - 1)) << SRC_BITS) | sv[g].y;
            int w2 = (ev[g].z << (SRC_BITS + 8)) | ((dv[g].z & (BNODES - 1)) << SRC_BITS) | sv[g].z;
            int w3 = (ev[g].w << (SRC_BITS + 8)) | ((dv[g].w & (BNODES - 1)) << SRC_BITS) | sv[g].w;
            int b0 = dv[g].x >> BSHIFT, b1_ = dv[g].y >> BSHIFT;
            int b2_ = dv[g].z >> BSHIFT, b3 = dv[g].w >> BSHIFT;
            stage[bkOff[b0] + atomicAdd(&hist[b0], 1)] = w0;
            stage[bkOff[b1_] + atomicAdd(&hist[b1_], 1)] = w1;
            stage[bkOff[b2_] + atomicAdd(&hist[b2_], 1)] = w2;
            stage[bkOff[b3] + atomicAdd(&hist[b3], 1)] = w3;
        }
        __syncthreads();
        // coalesced drain: consecutive threads -> consecutive global addresses
        for (int j = tid; j < CHUNK; j += PB) {
            int lo = 0, hi = MAXB;               // lower-bound on bkOff
            while (hi - lo > 1) {
                int mid = (lo + hi) >> 1;
                if (bkOff[mid] <= j) lo = mid; else hi = mid;
            }
            pack[locS[lo] + (j - bkOff[lo])] = stage[j];
        }
    } else {                                   // tail chunk: scalar direct scatter
        for (int j = start + tid; j < end; j += PB)
            atomicAdd(&hist[dst[j] >> BSHIFT], 1);
        __syncthreads();
        for (int i = tid; i < nbk; i += PB) {
            int h = hist[i];
            locS[i] = h ? i * cap + atomicAdd(&cursor[i], h) : 0;
        }
        __syncthreads();
        for (int j = start + tid; j < end; j += PB) {
            int d = dst[j];
            int slot = atomicAdd(&locS[d >> BSHIFT], 1);
            pack[slot] = (etype[j] << (SRC_BITS + 8)) | ((d & (BNODES - 1)) << SRC_BITS) | src[j];
        }
    }

    // ---- fused table: blocks 0..7 each compute a 76-entry segment, wave-parallel ----
    for (int seg = blockIdx.x; seg < 8; seg += gridDim.x) {
        int wid = threadIdx.x >> 6, lane = threadIdx.x & 63;
        int e0 = seg * 76;
        int e1 = min(e0 + 76, TABLE_SIZE);
        for (int e = e0 + wid; e < e1; e += PB / 64) {
            int et = e >> 4, ht = (e >> 2) & 3, tt = e & 3;
            float h = W1[et * HIDDEN + lane]
                    + W1[(NUM_EDGE_TYPES + ht) * HIDDEN + lane]
                    + W1[(NUM_EDGE_TYPES + NUM_NODE_TYPES + tt) * HIDDEN + lane]
                    + b1[lane];
            float u = 0.7978845608028654f * (h + 0.044715f * h * h * h);
            float g = 0.5f * h * (1.0f + tanhf(u));
            float v = g * W2[lane];
            v += __shfl_xor(v, 32, 64);
            v += __shfl_xor(v, 16, 64);
            v += __shfl_xor(v, 8, 64);
            v += __shfl_xor(v, 4, 64);
            v += __shfl_xor(v, 2, 64);
            v += __shfl_xor(v, 1, 64);
            if (lane == 0) table[e] = 1.0f / (1.0f + expf(-(v + b2[0])));
        }
    }
}

// ---- sort bucket by dstLow (r4/r5-verified, unchanged): ONE int4 global read
// into LDS (hist fused), LDS->LDS rank-scatter, int4 write-back, offsets, base. ----
__global__ void sort_base_kernel(int* __restrict__ pack, const int* __restrict__ cursor,
                                 const int* __restrict__ ntype, const float* __restrict__ table,
                                 float* __restrict__ base, int* __restrict__ nodeOffG,
                                 int N, int cap) {
    __shared__ int rawL[CAPC];
    __shared__ int sortedL[CAPC];
    __shared__ float tbl[TABLE_SIZE];
    __shared__ int nodeCnt[BNODES];
    __shared__ int nodeOff[BNODES + 1];
    __shared__ unsigned char ntLoc[BNODES];
    int b = blockIdx.x;
    int node0 = b << BSHIFT;
    int tid = threadIdx.x;
    int st = b * cap;                 // cap is 256-aligned -> st*4 bytes is 16B-aligned
    int c = min(cursor[b], cap);

    if (tid < TABLE_SIZE) tbl[tid] = table[tid];
    if (tid < BNODES) {
        nodeCnt[tid] = 0;
        int n = node0 + tid;
        ntLoc[tid] = (n < N) ? (unsigned char)ntype[n] : 0;
    }
    __syncthreads();

    int c4 = c & ~3;
    for (int j = tid * 4; j < c4; j += HB * 4) {
        int4 v = *(const int4*)(pack + st + j);
        *(int4*)(rawL + j) = v;
        atomicAdd(&nodeCnt[(v.x >> SRC_BITS) & (BNODES - 1)], 1);
        atomicAdd(&nodeCnt[(v.y >> SRC_BITS) & (BNODES - 1)], 1);
        atomicAdd(&nodeCnt[(v.z >> SRC_BITS) & (BNODES - 1)], 1);
        atomicAdd(&nodeCnt[(v.w >> SRC_BITS) & (BNODES - 1)], 1);
    }
    for (int j = c4 + tid; j < c; j += HB) {
        int p = pack[st + j];
        rawL[j] = p;
        atomicAdd(&nodeCnt[(p >> SRC_BITS) & (BNODES - 1)], 1);
    }
    __syncthreads();

    if (tid < 64) {
        int lane = tid;
        int v0 = nodeCnt[lane * 4], v1 = nodeCnt[lane * 4 + 1];
        int v2 = nodeCnt[lane * 4 + 2], v3 = nodeCnt[lane * 4 + 3];
        int s = v0 + v1 + v2 + v3;
        int inc = s;
        for (int d = 1; d < 64; d <<= 1) {
            int t = __shfl_up(inc, d, 64);
            if (lane >= d) inc += t;
        }
        int excl = inc - s;
        nodeOff[lane * 4]     = excl;
        nodeOff[lane * 4 + 1] = excl + v0;
        nodeOff[lane * 4 + 2] = excl + v0 + v1;
        nodeOff[lane * 4 + 3] = excl + v0 + v1 + v2;
        if (lane == 63) nodeOff[BNODES] = inc;
    }
    __syncthreads();
    if (tid < BNODES) nodeCnt[tid] = 0;  // reuse as rank cursor
    __syncthreads();

    {
        int j = tid;
        for (; j + HB < c; j += 2 * HB) {
            int p0 = rawL[j];
            int p1 = rawL[j + HB];
            int dl0 = (p0 >> SRC_BITS) & (BNODES - 1);
            int dl1 = (p1 >> SRC_BITS) & (BNODES - 1);
            int r0 = atomicAdd(&nodeCnt[dl0], 1);
            int r1 = atomicAdd(&nodeCnt[dl1], 1);
            sortedL[nodeOff[dl0] + r0] = p0;
            sortedL[nodeOff[dl1] + r1] = p1;
        }
        if (j < c) {
            int p = rawL[j];
            int dl = (p >> SRC_BITS) & (BNODES - 1);
            int r = atomicAdd(&nodeCnt[dl], 1);
            sortedL[nodeOff[dl] + r] = p;
        }
    }
    __syncthreads();

    for (int j = tid * 4; j < c4; j += HB * 4)
        *(int4*)(pack + st + j) = *(const int4*)(sortedL + j);
    for (int j = c4 + tid; j < c; j += HB) pack[st + j] = sortedL[j];
    if (tid < BNODES) nodeOffG[(b << BSHIFT) + tid] = nodeOff[tid];

    int node = tid >> 2, l = tid & 3;
    int lo = nodeOff[node], hi = nodeOff[node + 1];
    int nt = ntLoc[node];
    float s = 0.0f;
    int j = lo + l;
    for (; j + 4 < hi; j += 8) {
        int p0 = sortedL[j], p1 = sortedL[j + 4];
        s += tbl[((((unsigned)p0) >> (SRC_BITS + 8)) << 4) | (ntype[p0 & SRC_MASK] << 2) | nt]
           + tbl[((((unsigned)p1) >> (SRC_BITS + 8)) << 4) | (ntype[p1 & SRC_MASK] << 2) | nt];
    }
    if (j < hi) {
        int p = sortedL[j];
        s += tbl[((((unsigned)p) >> (SRC_BITS + 8)) << 4) | (ntype[p & SRC_MASK] << 2) | nt];
    }
    s += __shfl_xor(s, 1, 64);
    s += __shfl_xor(s, 2, 64);
    int n = node0 + node;
    if (l == 0 && n < N) base[n] = s;
}

// ---- hops 2-4 (r4-verified, unchanged): CSR segmented sums, 4 blocks/bucket,
// 8 lanes/node. Atomic-free, coalesced pack reads. ----
__global__ __launch_bounds__(512)
void hop_csr_kernel(const int* __restrict__ pack, const int* __restrict__ nodeOffG,
                    const int* __restrict__ cursor, const float* __restrict__ base,
                    const float* __restrict__ prev, float* __restrict__ out,
                    int N, int cap) {
    __shared__ int off[65];
    int blk = blockIdx.x;
    int b = blk >> 2;
    int q = blk & 3;
    int tid = threadIdx.x;
    int st = b * cap;
    int nodeBase = (b << BSHIFT) + q * 64;
    if (tid < 64) off[tid] = nodeOffG[nodeBase + tid];
    else if (tid == 64)
        off[64] = (q == 3) ? min(cursor[b], cap) : nodeOffG[nodeBase + 64];
    __syncthreads();
    int node = tid >> 3, l = tid & 7;   // node in 0..63, 8 lanes per node
    int lo = off[node], hi = off[node + 1];
    float s = 0.0f;
    int j = st + lo + l;
    int hiG = st + hi;
    for (; j + 8 < hiG; j += 16) {
        int p0 = pack[j], p1 = pack[j + 8];
        s += prev[p0 & SRC_MASK] + prev[p1 & SRC_MASK];
    }
    if (j < hiG) s += prev[pack[j] & SRC_MASK];
    s += __shfl_xor(s, 1, 64);
    s += __shfl_xor(s, 2, 64);
    s += __shfl_xor(s, 4, 64);
    int n = nodeBase + node;
    if (l == 0 && n < N) out[n] = base[n] + s;
}

// ================= edge-parallel atomic fallback (tiny ws) =================
__global__ void edge_base_kernel(const int* __restrict__ src, const int* __restrict__ dst,
                                 const int* __restrict__ etype, const int* __restrict__ ntype,
                                 const float* __restrict__ table, float* __restrict__ base, int E) {
    __shared__ float tbl[TABLE_SIZE];
    for (int i = threadIdx.x; i < TABLE_SIZE; i += blockDim.x) tbl[i] = table[i];
    __syncthreads();
    int e = blockIdx.x * blockDim.x + threadIdx.x;
    if (e >= E) return;
    int s = src[e];
    int d = dst[e];
    int idx = (etype[e] << 4) | (ntype[s] << 2) | ntype[d];
    atomicAdd(base + d, tbl[idx]);
}

__global__ void copy_kernel(const float* __restrict__ in, float* __restrict__ out, int N) {
    int i = blockIdx.x * blockDim.x + threadIdx.x;
    if (i < N) out[i] = in[i];
}

__global__ void edge_hop_kernel(const int* __restrict__ src, const int* __restrict__ dst,
                                const float* __restrict__ prev, float* __restrict__ next, int E) {
    int e = blockIdx.x * blockDim.x + threadIdx.x;
    if (e >= E) return;
    atomicAdd(next + dst[e], prev[src[e]]);
}

extern "C" void kernel_launch(void* const* d_in, const int* in_sizes, int n_in,
                              void* d_out, int out_size, void* d_ws, size_t ws_size,
                              hipStream_t stream) {
    const int* edge_index = (const int*)d_in[0];   // (2, E)
    const int* etype      = (const int*)d_in[1];   // (E,)
    const int* ntype      = (const int*)d_in[2];   // (N,)
    const float* W1       = (const float*)d_in[3];
    const float* b1       = (const float*)d_in[4];
    const float* W2       = (const float*)d_in[5];
    const float* b2       = (const float*)d_in[6];

    const int E = in_sizes[1];
    const int N = in_sizes[2];
    const int* src = edge_index;
    const int* dst = edge_index + E;
    float* out = (float*)d_out;

    const int nbk = (N + BNODES - 1) >> BSHIFT;      // 391 for N=100000
    const int nChunks = (E + CHUNK - 1) / CHUNK;     // 391 for E=1.6M

    int cap = ((E / (nbk > 0 ? nbk : 1)) * 3 / 2 + 255) & ~255;  // 1.5x mean, 256-aligned
    if (cap < 512) cap = 512;
    size_t packElems = (size_t)nbk * cap;

    // ws layout (4B units): pack[nbk*cap] | cursor[MAXB] | nodeOffG[nbk*256]
    //                       | table[1024] | base[N] | bufA[N] | bufB[N]
    size_t need = (packElems + MAXB + (size_t)nbk * BNODES + 1024 + (size_t)3 * N) * 4 + 256;

    if (ws_size >= need && nbk <= MAXB && cap <= CAPC) {
        int* pack     = (int*)d_ws;
        int* cursor   = pack + packElems;
        int* nodeOffG = cursor + MAXB;
        float* table  = (float*)(nodeOffG + (size_t)nbk * BNODES);
        float* base   = table + 1024;
        float* bufA   = base + N;
        float* bufB   = bufA + N;

        hipMemsetAsync(cursor, 0, MAXB * sizeof(int), stream);
        partition_kernel<<<nChunks, PB, 0, stream>>>(src, dst, etype, cursor, pack, E, nbk, cap,
                                                     W1, b1, W2, b2, table);
        sort_base_kernel<<<nbk, HB, 0, stream>>>(pack, cursor, ntype, table, base, nodeOffG, N, cap);
        hop_csr_kernel<<<4 * nbk, 512, 0, stream>>>(pack, nodeOffG, cursor, base, base, bufA, N, cap);
        hop_csr_kernel<<<4 * nbk, 512, 0, stream>>>(pack, nodeOffG, cursor, base, bufA, bufB, N, cap);
        hop_csr_kernel<<<4 * nbk, 512, 0, stream>>>(pack, nodeOffG, cursor, base, bufB, out, N, cap);
    } else {
        // fallback: edge-parallel atomic path
        float* table = (float*)d_ws;
        float* base  = table + 1024;
        float* bufA  = base + N;
        float* bufB  = bufA + N;
        const int eb = (E + 255) / 256;
        const int nb = (N + 255) / 256;

        hipMemsetAsync(base, 0, (size_t)N * sizeof(float), stream);
        table_kernel<<<(TABLE_SIZE + 255) / 256, 256, 0, stream>>>(W1, b1, W2, b2, table);

        edge_base_kernel<<<eb, 256, 0, stream>>>(src, dst, etype, ntype, table, base, E);
        copy_kernel<<<nb, 256, 0, stream>>>(base, bufA, N);
        edge_hop_kernel<<<eb, 256, 0, stream>>>(src, dst, base, bufA, E);
        copy_kernel<<<nb, 256, 0, stream>>>(base, bufB, N);
        edge_hop_kernel<<<eb, 256, 0, stream>>>(src, dst, bufA, bufB, E);
        copy_kernel<<<nb, 256, 0, stream>>>(base, out, N);
        edge_hop_kernel<<<eb, 256, 0, stream>>>(src, dst, bufB, out, E);
    }
}

// Round 10
// 133.914 us; speedup vs baseline: 3.1607x; 1.0289x over previous
//
#include <hip/hip_runtime.h>

#define NUM_EDGE_TYPES 38
#define NUM_NODE_TYPES 4
#define HIDDEN 64
#define TABLE_SIZE (NUM_EDGE_TYPES * NUM_NODE_TYPES * NUM_NODE_TYPES)  // 608
#define SRC_BITS 17
#define SRC_MASK ((1 << SRC_BITS) - 1)   // N_NODES = 100000 < 131072
#define BSHIFT 8                          // 256 dst nodes per bucket (best measured: r0/r4)
#define BNODES 256
#define MAXB 512                          // supports N up to 131072
#define PB 512                            // partition block size
#define EPT 16                            // edges per thread in partition
#define CHUNK (PB * EPT)                  // 8192 edges per partition chunk (halves claim count)
#define HB 1024                           // sort block size
#define CAPC 6144                         // max bucket capacity (LDS sort)
// pack layout: [31]=0 | et[30:25] | dstLow[24:17] | src[16:0]

__device__ __forceinline__ float table_entry(int i, const float* __restrict__ W1,
                                             const float* __restrict__ b1,
                                             const float* __restrict__ W2,
                                             const float* __restrict__ b2) {
    int et = i >> 4, ht = (i >> 2) & 3, tt = i & 3;
    const float* r0 = W1 + et * HIDDEN;
    const float* r1 = W1 + (NUM_EDGE_TYPES + ht) * HIDDEN;
    const float* r2 = W1 + (NUM_EDGE_TYPES + NUM_NODE_TYPES + tt) * HIDDEN;
    float acc = b2[0];
#pragma unroll 8
    for (int k = 0; k < HIDDEN; ++k) {
        float h = r0[k] + r1[k] + r2[k] + b1[k];
        float u = 0.7978845608028654f * (h + 0.044715f * h * h * h);
        float g = 0.5f * h * (1.0f + tanhf(u));
        acc += g * W2[k];
    }
    return 1.0f / (1.0f + expf(-acc));
}

// standalone table (fallback path)
__global__ void table_kernel(const float* __restrict__ W1, const float* __restrict__ b1,
                             const float* __restrict__ W2, const float* __restrict__ b2,
                             float* __restrict__ table) {
    int i = blockIdx.x * blockDim.x + threadIdx.x;
    if (i < TABLE_SIZE) table[i] = table_entry(i, W1, b1, W2, b2);
}

// ---- single-pass partition: 16 edges/thread (4x int4 per array), LDS hist,
// ONE claim phase per 8192 edges, scatter.
// Blocks 0-7 also compute 76 table entries each, wave-parallel, after their chunk. ----
__global__ __launch_bounds__(PB)
void partition_kernel(const int* __restrict__ src, const int* __restrict__ dst,
                      const int* __restrict__ etype, int* __restrict__ cursor,
                      int* __restrict__ pack, int E, int nbk, int cap,
                      const float* __restrict__ W1, const float* __restrict__ b1,
                      const float* __restrict__ W2, const float* __restrict__ b2,
                      float* __restrict__ table) {
    __shared__ int hist[MAXB];
    __shared__ int locCur[MAXB];
    for (int i = threadIdx.x; i < nbk; i += PB) hist[i] = 0;
    __syncthreads();
    int start = blockIdx.x * CHUNK;
    int end = min(start + CHUNK, E);
    if (end - start == CHUNK) {               // full chunk: 16 edges/thread
        int4 dv[4], sv[4], ev[4];
#pragma unroll
        for (int g = 0; g < 4; ++g) {
            int j = start + g * (PB * 4) + threadIdx.x * 4;
            dv[g] = *(const int4*)(dst + j);
        }
#pragma unroll
        for (int g = 0; g < 4; ++g) {
            atomicAdd(&hist[dv[g].x >> BSHIFT], 1);
            atomicAdd(&hist[dv[g].y >> BSHIFT], 1);
            atomicAdd(&hist[dv[g].z >> BSHIFT], 1);
            atomicAdd(&hist[dv[g].w >> BSHIFT], 1);
        }
#pragma unroll
        for (int g = 0; g < 4; ++g) {
            int j = start + g * (PB * 4) + threadIdx.x * 4;
            sv[g] = *(const int4*)(src + j);
            ev[g] = *(const int4*)(etype + j);
        }
        __syncthreads();
        for (int i = threadIdx.x; i < nbk; i += PB) {
            int h = hist[i];
            locCur[i] = h ? i * cap + atomicAdd(&cursor[i], h) : 0;
        }
        __syncthreads();
#pragma unroll
        for (int g = 0; g < 4; ++g) {
            int t0 = atomicAdd(&locCur[dv[g].x >> BSHIFT], 1);
            int t1 = atomicAdd(&locCur[dv[g].y >> BSHIFT], 1);
            int t2 = atomicAdd(&locCur[dv[g].z >> BSHIFT], 1);
            int t3 = atomicAdd(&locCur[dv[g].w >> BSHIFT], 1);
            pack[t0] = (ev[g].x << (SRC_BITS + 8)) | ((dv[g].x & (BNODES - 1)) << SRC_BITS) | sv[g].x;
            pack[t1] = (ev[g].y << (SRC_BITS + 8)) | ((dv[g].y & (BNODES - 1)) << SRC_BITS) | sv[g].y;
            pack[t2] = (ev[g].z << (SRC_BITS + 8)) | ((dv[g].z & (BNODES - 1)) << SRC_BITS) | sv[g].z;
            pack[t3] = (ev[g].w << (SRC_BITS + 8)) | ((dv[g].w & (BNODES - 1)) << SRC_BITS) | sv[g].w;
        }
    } else {                                   // tail chunk: scalar
        for (int j = start + threadIdx.x; j < end; j += PB)
            atomicAdd(&hist[dst[j] >> BSHIFT], 1);
        __syncthreads();
        for (int i = threadIdx.x; i < nbk; i += PB) {
            int h = hist[i];
            locCur[i] = h ? i * cap + atomicAdd(&cursor[i], h) : 0;
        }
        __syncthreads();
        for (int j = start + threadIdx.x; j < end; j += PB) {
            int d = dst[j];
            int slot = atomicAdd(&locCur[d >> BSHIFT], 1);
            pack[slot] = (etype[j] << (SRC_BITS + 8)) | ((d & (BNODES - 1)) << SRC_BITS) | src[j];
        }
    }

    // ---- fused table: blocks 0..7 each compute a 76-entry segment, wave-parallel ----
    for (int seg = blockIdx.x; seg < 8; seg += gridDim.x) {
        int wid = threadIdx.x >> 6, lane = threadIdx.x & 63;
        int e0 = seg * 76;
        int e1 = min(e0 + 76, TABLE_SIZE);
        for (int e = e0 + wid; e < e1; e += PB / 64) {
            int et = e >> 4, ht = (e >> 2) & 3, tt = e & 3;
            float h = W1[et * HIDDEN + lane]
                    + W1[(NUM_EDGE_TYPES + ht) * HIDDEN + lane]
                    + W1[(NUM_EDGE_TYPES + NUM_NODE_TYPES + tt) * HIDDEN + lane]
                    + b1[lane];
            float u = 0.7978845608028654f * (h + 0.044715f * h * h * h);
            float g = 0.5f * h * (1.0f + tanhf(u));
            float v = g * W2[lane];
            v += __shfl_xor(v, 32, 64);
            v += __shfl_xor(v, 16, 64);
            v += __shfl_xor(v, 8, 64);
            v += __shfl_xor(v, 4, 64);
            v += __shfl_xor(v, 2, 64);
            v += __shfl_xor(v, 1, 64);
            if (lane == 0) table[e] = 1.0f / (1.0f + expf(-(v + b2[0])));
        }
    }
}

// ---- sort bucket by dstLow (r0/r4-verified): ONE int4 global read into LDS (hist
// fused), LDS->LDS rank-scatter, int4 write-back, per-node offsets, base[] sums. ----
__global__ void sort_base_kernel(int* __restrict__ pack, const int* __restrict__ cursor,
                                 const int* __restrict__ ntype, const float* __restrict__ table,
                                 float* __restrict__ base, int* __restrict__ nodeOffG,
                                 int N, int cap) {
    __shared__ int rawL[CAPC];
    __shared__ int sortedL[CAPC];
    __shared__ float tbl[TABLE_SIZE];
    __shared__ int nodeCnt[BNODES];
    __shared__ int nodeOff[BNODES + 1];
    __shared__ unsigned char ntLoc[BNODES];
    int b = blockIdx.x;
    int node0 = b << BSHIFT;
    int tid = threadIdx.x;
    int st = b * cap;                 // cap is 256-aligned -> st*4 bytes is 16B-aligned
    int c = min(cursor[b], cap);

    if (tid < TABLE_SIZE) tbl[tid] = table[tid];
    if (tid < BNODES) {
        nodeCnt[tid] = 0;
        int n = node0 + tid;
        ntLoc[tid] = (n < N) ? (unsigned char)ntype[n] : 0;
    }
    __syncthreads();

    // pass 1: int4 load into rawL + histogram by dstLow (single global read)
    int c4 = c & ~3;
    for (int j = tid * 4; j < c4; j += HB * 4) {
        int4 v = *(const int4*)(pack + st + j);
        *(int4*)(rawL + j) = v;
        atomicAdd(&nodeCnt[(v.x >> SRC_BITS) & (BNODES - 1)], 1);
        atomicAdd(&nodeCnt[(v.y >> SRC_BITS) & (BNODES - 1)], 1);
        atomicAdd(&nodeCnt[(v.z >> SRC_BITS) & (BNODES - 1)], 1);
        atomicAdd(&nodeCnt[(v.w >> SRC_BITS) & (BNODES - 1)], 1);
    }
    for (int j = c4 + tid; j < c; j += HB) {
        int p = pack[st + j];
        rawL[j] = p;
        atomicAdd(&nodeCnt[(p >> SRC_BITS) & (BNODES - 1)], 1);
    }
    __syncthreads();

    // exclusive scan of 256 counts on wave 0
    if (tid < 64) {
        int lane = tid;
        int v0 = nodeCnt[lane * 4], v1 = nodeCnt[lane * 4 + 1];
        int v2 = nodeCnt[lane * 4 + 2], v3 = nodeCnt[lane * 4 + 3];
        int s = v0 + v1 + v2 + v3;
        int inc = s;
        for (int d = 1; d < 64; d <<= 1) {
            int t = __shfl_up(inc, d, 64);
            if (lane >= d) inc += t;
        }
        int excl = inc - s;
        nodeOff[lane * 4]     = excl;
        nodeOff[lane * 4 + 1] = excl + v0;
        nodeOff[lane * 4 + 2] = excl + v0 + v1;
        nodeOff[lane * 4 + 3] = excl + v0 + v1 + v2;
        if (lane == 63) nodeOff[BNODES] = inc;
    }
    __syncthreads();
    if (tid < BNODES) nodeCnt[tid] = 0;  // reuse as rank cursor
    __syncthreads();

    // pass 2: rank + scatter LDS -> LDS, two independent chains per iteration
    {
        int j = tid;
        for (; j + HB < c; j += 2 * HB) {
            int p0 = rawL[j];
            int p1 = rawL[j + HB];
            int dl0 = (p0 >> SRC_BITS) & (BNODES - 1);
            int dl1 = (p1 >> SRC_BITS) & (BNODES - 1);
            int r0 = atomicAdd(&nodeCnt[dl0], 1);
            int r1 = atomicAdd(&nodeCnt[dl1], 1);
            sortedL[nodeOff[dl0] + r0] = p0;
            sortedL[nodeOff[dl1] + r1] = p1;
        }
        if (j < c) {
            int p = rawL[j];
            int dl = (p >> SRC_BITS) & (BNODES - 1);
            int r = atomicAdd(&nodeCnt[dl], 1);
            sortedL[nodeOff[dl] + r] = p;
        }
    }
    __syncthreads();

    // int4 write-back of sorted slice + per-node offsets
    for (int j = tid * 4; j < c4; j += HB * 4)
        *(int4*)(pack + st + j) = *(const int4*)(sortedL + j);
    for (int j = c4 + tid; j < c; j += HB) pack[st + j] = sortedL[j];
    if (tid < BNODES) nodeOffG[(b << BSHIFT) + tid] = nodeOff[tid];

    // base: 4 lanes/node segmented sum of table values
    int node = tid >> 2, l = tid & 3;
    int lo = nodeOff[node], hi = nodeOff[node + 1];
    int nt = ntLoc[node];
    float s = 0.0f;
    int j = lo + l;
    for (; j + 4 < hi; j += 8) {
        int p0 = sortedL[j], p1 = sortedL[j + 4];
        s += tbl[((((unsigned)p0) >> (SRC_BITS + 8)) << 4) | (ntype[p0 & SRC_MASK] << 2) | nt]
           + tbl[((((unsigned)p1) >> (SRC_BITS + 8)) << 4) | (ntype[p1 & SRC_MASK] << 2) | nt];
    }
    if (j < hi) {
        int p = sortedL[j];
        s += tbl[((((unsigned)p) >> (SRC_BITS + 8)) << 4) | (ntype[p & SRC_MASK] << 2) | nt];
    }
    s += __shfl_xor(s, 1, 64);
    s += __shfl_xor(s, 2, 64);
    int n = node0 + node;
    if (l == 0 && n < N) base[n] = s;
}

// ---- hops 2-4 (r4-verified): CSR segmented sums, 4 blocks per bucket (64 nodes),
// 8 lanes/node for latency hiding. Atomic-free, coalesced pack reads. ----
__global__ __launch_bounds__(512)
void hop_csr_kernel(const int* __restrict__ pack, const int* __restrict__ nodeOffG,
                    const int* __restrict__ cursor, const float* __restrict__ base,
                    const float* __restrict__ prev, float* __restrict__ out,
                    int N, int cap) {
    __shared__ int off[65];
    int blk = blockIdx.x;
    int b = blk >> 2;
    int q = blk & 3;
    int tid = threadIdx.x;
    int st = b * cap;
    int nodeBase = (b << BSHIFT) + q * 64;
    if (tid < 64) off[tid] = nodeOffG[nodeBase + tid];
    else if (tid == 64)
        off[64] = (q == 3) ? min(cursor[b], cap) : nodeOffG[nodeBase + 64];
    __syncthreads();
    int node = tid >> 3, l = tid & 7;   // node in 0..63, 8 lanes per node
    int lo = off[node], hi = off[node + 1];
    float s = 0.0f;
    int j = st + lo + l;
    int hiG = st + hi;
    for (; j + 8 < hiG; j += 16) {
        int p0 = pack[j], p1 = pack[j + 8];
        s += prev[p0 & SRC_MASK] + prev[p1 & SRC_MASK];
    }
    if (j < hiG) s += prev[pack[j] & SRC_MASK];
    s += __shfl_xor(s, 1, 64);
    s += __shfl_xor(s, 2, 64);
    s += __shfl_xor(s, 4, 64);
    int n = nodeBase + node;
    if (l == 0 && n < N) out[n] = base[n] + s;
}

// ================= edge-parallel atomic fallback (tiny ws) =================
__global__ void edge_base_kernel(const int* __restrict__ src, const int* __restrict__ dst,
                                 const int* __restrict__ etype, const int* __restrict__ ntype,
                                 const float* __restrict__ table, float* __restrict__ base, int E) {
    __shared__ float tbl[TABLE_SIZE];
    for (int i = threadIdx.x; i < TABLE_SIZE; i += blockDim.x) tbl[i] = table[i];
    __syncthreads();
    int e = blockIdx.x * blockDim.x + threadIdx.x;
    if (e >= E) return;
    int s = src[e];
    int d = dst[e];
    int idx = (etype[e] << 4) | (ntype[s] << 2) | ntype[d];
    atomicAdd(base + d, tbl[idx]);
}

__global__ void copy_kernel(const float* __restrict__ in, float* __restrict__ out, int N) {
    int i = blockIdx.x * blockDim.x + threadIdx.x;
    if (i < N) out[i] = in[i];
}

__global__ void edge_hop_kernel(const int* __restrict__ src, const int* __restrict__ dst,
                                const float* __restrict__ prev, float* __restrict__ next, int E) {
    int e = blockIdx.x * blockDim.x + threadIdx.x;
    if (e >= E) return;
    atomicAdd(next + dst[e], prev[src[e]]);
}

extern "C" void kernel_launch(void* const* d_in, const int* in_sizes, int n_in,
                              void* d_out, int out_size, void* d_ws, size_t ws_size,
                              hipStream_t stream) {
    const int* edge_index = (const int*)d_in[0];   // (2, E)
    const int* etype      = (const int*)d_in[1];   // (E,)
    const int* ntype      = (const int*)d_in[2];   // (N,)
    const float* W1       = (const float*)d_in[3];
    const float* b1       = (const float*)d_in[4];
    const float* W2       = (const float*)d_in[5];
    const float* b2       = (const float*)d_in[6];

    const int E = in_sizes[1];
    const int N = in_sizes[2];
    const int* src = edge_index;
    const int* dst = edge_index + E;
    float* out = (float*)d_out;

    const int nbk = (N + BNODES - 1) >> BSHIFT;      // 391 for N=100000
    const int nChunks = (E + CHUNK - 1) / CHUNK;     // 196 for E=1.6M

    int cap = ((E / (nbk > 0 ? nbk : 1)) * 3 / 2 + 255) & ~255;  // 1.5x mean, 256-aligned
    if (cap < 512) cap = 512;
    size_t packElems = (size_t)nbk * cap;

    // ws layout (4B units): pack[nbk*cap] | cursor[MAXB] | nodeOffG[nbk*256]
    //                       | table[1024] | base[N] | bufA[N] | bufB[N]
    size_t need = (packElems + MAXB + (size_t)nbk * BNODES + 1024 + (size_t)3 * N) * 4 + 256;

    if (ws_size >= need && nbk <= MAXB && cap <= CAPC) {
        int* pack     = (int*)d_ws;
        int* cursor   = pack + packElems;
        int* nodeOffG = cursor + MAXB;
        float* table  = (float*)(nodeOffG + (size_t)nbk * BNODES);
        float* base   = table + 1024;
        float* bufA   = base + N;
        float* bufB   = bufA + N;

        hipMemsetAsync(cursor, 0, MAXB * sizeof(int), stream);
        partition_kernel<<<nChunks, PB, 0, stream>>>(src, dst, etype, cursor, pack, E, nbk, cap,
                                                     W1, b1, W2, b2, table);
        sort_base_kernel<<<nbk, HB, 0, stream>>>(pack, cursor, ntype, table, base, nodeOffG, N, cap);
        hop_csr_kernel<<<4 * nbk, 512, 0, stream>>>(pack, nodeOffG, cursor, base, base, bufA, N, cap);
        hop_csr_kernel<<<4 * nbk, 512, 0, stream>>>(pack, nodeOffG, cursor, base, bufA, bufB, N, cap);
        hop_csr_kernel<<<4 * nbk, 512, 0, stream>>>(pack, nodeOffG, cursor, base, bufB, out, N, cap);
    } else {
        // fallback: edge-parallel atomic path
        float* table = (float*)d_ws;
        float* base  = table + 1024;
        float* bufA  = base + N;
        float* bufB  = bufA + N;
        const int eb = (E + 255) / 256;
        const int nb = (N + 255) / 256;

        hipMemsetAsync(base, 0, (size_t)N * sizeof(float), stream);
        table_kernel<<<(TABLE_SIZE + 255) / 256, 256, 0, stream>>>(W1, b1, W2, b2, table);

        edge_base_kernel<<<eb, 256, 0, stream>>>(src, dst, etype, ntype, table, base, E);
        copy_kernel<<<nb, 256, 0, stream>>>(base, bufA, N);
        edge_hop_kernel<<<eb, 256, 0, stream>>>(src, dst, base, bufA, E);
        copy_kernel<<<nb, 256, 0, stream>>>(base, bufB, N);
        edge_hop_kernel<<<eb, 256, 0, stream>>>(src, dst, bufA, bufB, E);
        copy_kernel<<<nb, 256, 0, stream>>>(base, out, N);
        edge_hop_kernel<<<eb, 256, 0, stream>>>(src, dst, bufB, out, E);
    }
}